// Round 5
// baseline (233.433 us; speedup 1.0000x reference)
//
#include <hip/hip_runtime.h>
#include <hip/hip_bf16.h>

// Problem constants
#define DM     768
#define HEADS  12
#define DK     64
#define SQ     2048
#define BATCH  2
#define ROWS   4096   // BATCH * SQ
#define KTILES 24     // DM / 32

typedef __attribute__((ext_vector_type(4))) float f32x4;
typedef __bf16 bf16x8 __attribute__((ext_vector_type(8)));
typedef unsigned short u16x8 __attribute__((ext_vector_type(8)));

#define QSCALE 0.180336880f   // (1/sqrt(64)) * log2(e): scores feed exp2f

static __device__ __forceinline__ unsigned short f2bf(float f) {
    union { float f; unsigned u; } v; v.f = f;
    unsigned u = v.u;
    unsigned lsb = (u >> 16) & 1u;
    u += 0x7fffu + lsb;              // round-to-nearest-even
    return (unsigned short)(u >> 16);
}

static __device__ __forceinline__ unsigned pack_bf16(float a, float b) {
    __hip_bfloat162 h = __float22bfloat162_rn(make_float2(a, b));  // v_cvt_pk_bf16_f32
    unsigned u;
    __builtin_memcpy(&u, &h, 4);
    return u;
}

static __device__ __forceinline__ bf16x8 load_bf16x8(const unsigned short* p) {
    u16x8 u = *(const u16x8*)p;      // 16B load
    return __builtin_bit_cast(bf16x8, u);
}

// Async global->LDS DMA: 64 lanes x 16B; LDS dest = uniform base + lane*16.
static __device__ __forceinline__ void gld_lds16(const unsigned short* g, unsigned short* l) {
    __builtin_amdgcn_global_load_lds((const __attribute__((address_space(1))) void*)g,
                                     (__attribute__((address_space(3))) void*)l,
                                     16, 0, 0);
}

// ---------- fp32 -> bf16 convert into FRAGMENT-LINEAR order (3 tensors) -------
__global__ __launch_bounds__(256) void cvt_frag3(const float* __restrict__ X0,
                                                 const float* __restrict__ X1,
                                                 const float* __restrict__ X2,
                                                 unsigned short* __restrict__ A0,
                                                 unsigned short* __restrict__ A1,
                                                 unsigned short* __restrict__ A2) {
    int z = blockIdx.z;
    const float* X = z == 0 ? X0 : z == 1 ? X1 : X2;
    unsigned short* A = z == 0 ? A0 : z == 1 ? A1 : A2;
    int p = blockIdx.x * 256 + threadIdx.x;
    int lane = p & 63;
    int g = p >> 6;
    int ks = g % KTILES;
    int mt = g / KTILES;
    int row = mt * 16 + (lane & 15);
    int k   = ks * 32 + (lane >> 4) * 8;
    const float* src = X + (size_t)row * DM + k;
    float4 v0 = *(const float4*)src;
    float4 v1 = *(const float4*)(src + 4);
    u16x8 o;
    o[0]=f2bf(v0.x); o[1]=f2bf(v0.y); o[2]=f2bf(v0.z); o[3]=f2bf(v0.w);
    o[4]=f2bf(v1.x); o[5]=f2bf(v1.y); o[6]=f2bf(v1.z); o[7]=f2bf(v1.w);
    *(u16x8*)(A + (size_t)p * 8) = o;
}

// ---------- weight transpose+convert into FRAGMENT-LINEAR order (4 weights) ---
__global__ __launch_bounds__(256) void wt_frag4(const float* __restrict__ W0,
                                                const float* __restrict__ W1,
                                                const float* __restrict__ W2,
                                                const float* __restrict__ W3,
                                                unsigned short* __restrict__ F0,
                                                unsigned short* __restrict__ F1,
                                                unsigned short* __restrict__ F2,
                                                unsigned short* __restrict__ F3) {
    int z = blockIdx.z;
    const float* W = z == 0 ? W0 : z == 1 ? W1 : z == 2 ? W2 : W3;
    unsigned short* F = z == 0 ? F0 : z == 1 ? F1 : z == 2 ? F2 : F3;
    int p = blockIdx.x * 256 + threadIdx.x;
    int lane = p & 63;
    int t = (p >> 6) & 3;
    int g = p >> 8;
    int ks = g % KTILES;
    int nb = g / KTILES;
    int n = nb * 64 + t * 16 + (lane & 15);
    int k = ks * 32 + (lane >> 4) * 8;
    u16x8 o;
#pragma unroll
    for (int j = 0; j < 8; ++j) o[j] = f2bf(W[(size_t)(k + j) * DM + n]);
    *(u16x8*)(F + (size_t)p * 8) = o;
}

// ---------------- QKV GEMM (fused): 64x64 wave tiles, LDS-staged weights ------
// Block = 2 waves = 128 rows x 64 cols. Weight frags for 4 k-steps (16KB)
// DMA'd to LDS double-buffered; A direct from global (frag-linear, coalesced).
__global__ __launch_bounds__(128) void gemm_qkv(const unsigned short* __restrict__ A0,
                                                const unsigned short* __restrict__ A1,
                                                const unsigned short* __restrict__ A2,
                                                const unsigned short* __restrict__ F0,
                                                const unsigned short* __restrict__ F1,
                                                const unsigned short* __restrict__ F2,
                                                const float* __restrict__ b0,
                                                const float* __restrict__ b1,
                                                const float* __restrict__ b2,
                                                unsigned short* __restrict__ Qo,
                                                unsigned short* __restrict__ Ko,
                                                unsigned short* __restrict__ Vo) {
    __shared__ __align__(16) unsigned short ldsB[2][8192];   // 16KB x2

    int z = blockIdx.z;
    const unsigned short* A = z == 0 ? A0 : z == 1 ? A1 : A2;
    const unsigned short* F = z == 0 ? F0 : z == 1 ? F1 : F2;
    const float* bias        = z == 0 ? b0 : z == 1 ? b1 : b2;

    int w    = threadIdx.x >> 6;
    int lane = threadIdx.x & 63;
    int l15  = lane & 15;
    int quad = lane >> 4;
    int m0 = blockIdx.y * 128 + w * 64;
    int nb = blockIdx.x;
    int mt0 = m0 >> 4;

    const unsigned short* Ap = A + (size_t)mt0 * KTILES * 512 + lane * 8;
    const unsigned short* Bsrc = F + (size_t)nb * KTILES * 4 * 512 + (w * 8) * 512 + lane * 8;
    unsigned short* Bdst = &ldsB[0][(w * 8) * 512];

    f32x4 acc[4][4];
#pragma unroll
    for (int i = 0; i < 4; ++i)
#pragma unroll
        for (int t = 0; t < 4; ++t) acc[i][t] = (f32x4){0.f, 0.f, 0.f, 0.f};

#define BSTAGE(buf, c) do { \
        _Pragma("unroll") \
        for (int i = 0; i < 8; ++i) \
            gld_lds16(Bsrc + (size_t)(c) * 8192 + i * 512, Bdst + (buf) * 8192 + i * 512); \
    } while (0)

    BSTAGE(0, 0);

    for (int c = 0; c < 6; ++c) {
        __syncthreads();
        if (c < 5) BSTAGE((c + 1) & 1, c + 1);
        const unsigned short* Bl = &ldsB[c & 1][0];
#pragma unroll
        for (int k4 = 0; k4 < 4; ++k4) {
            bf16x8 a[4];
#pragma unroll
            for (int i = 0; i < 4; ++i)
                a[i] = load_bf16x8(Ap + ((size_t)i * KTILES + c * 4 + k4) * 512);
#pragma unroll
            for (int t = 0; t < 4; ++t) {
                bf16x8 bb = load_bf16x8(Bl + (k4 * 4 + t) * 512 + lane * 8);
#pragma unroll
                for (int i = 0; i < 4; ++i)
                    acc[i][t] = __builtin_amdgcn_mfma_f32_16x16x32_bf16(a[i], bb, acc[i][t], 0, 0, 0);
            }
        }
    }
#undef BSTAGE

    float scale = (z == 0) ? QSCALE : 1.0f;
#pragma unroll
    for (int t = 0; t < 4; ++t) {
        int col = nb * 64 + t * 16 + l15;
        float bv = bias[col];
        int h = col >> 6, d = col & (DK - 1);
#pragma unroll
        for (int i = 0; i < 4; ++i)
#pragma unroll
            for (int r = 0; r < 4; ++r) {
                int row = m0 + i * 16 + quad * 4 + r;
                float v = (acc[i][t][r] + bv) * scale;
                int bb = row >> 11, s = row & (SQ - 1);
                size_t bh = (size_t)(bb * HEADS + h);
                if (z == 0) {
                    Qo[(bh * SQ + s) * DK + d] = f2bf(v);
                } else if (z == 1) {
                    int sc = s & 63;
                    Ko[(bh * (SQ / 64) + (s >> 6)) * 4096 + sc * 64 +
                       (((d >> 3) ^ ((sc >> 1) & 7)) << 3) + (d & 7)] = f2bf(v);
                } else {
                    int sc = s & 63;
                    Vo[(bh * (SQ / 64) + (s >> 6)) * 4096 + d * 64 +
                       (((sc >> 3) ^ ((d >> 1) & 7)) << 3) + (sc & 7)] = f2bf(v);
                }
            }
    }
}

// ---------------- Flash attention v4: 32 q-rows/wave, K/V frags shared --------
// 2 waves/block (64 q-rows). K/V 8KB chunks DMA'd to LDS double-buffered.
// exp2-softmax (Q pre-scaled by log2e/8), per-lane l-sums, one final reduce.
__global__ __launch_bounds__(128) void flash_attn(const unsigned short* __restrict__ Q,
                                                  const unsigned short* __restrict__ Kb,
                                                  const unsigned short* __restrict__ Vb,
                                                  unsigned short* __restrict__ Af) {
    __shared__ __align__(16) unsigned short ldsK[2][4096];    // 8KB x2
    __shared__ __align__(16) unsigned short ldsV[2][4096];    // 8KB x2
    __shared__ __align__(16) unsigned short ldsP[2][32 * 72]; // per-wave P (32 rows)

    int w    = threadIdx.x >> 6;
    int lane = threadIdx.x & 63;
    int l15  = lane & 15;
    int quad = lane >> 4;
    int b = blockIdx.z, h = blockIdx.y;
    int q0 = blockIdx.x * 64 + w * 32;

    size_t bh = (size_t)(b * HEADS + h);
    const unsigned short* Qp = Q  + (bh * SQ + q0) * DK;
    const unsigned short* KB = Kb + bh * (SQ / 64) * 4096;
    const unsigned short* VB = Vb + bh * (SQ / 64) * 4096;

    bf16x8 aq[2][2];
#pragma unroll
    for (int i = 0; i < 2; ++i) {
        aq[i][0] = load_bf16x8(Qp + (i * 16 + l15) * DK + quad * 8);
        aq[i][1] = load_bf16x8(Qp + (i * 16 + l15) * DK + 32 + quad * 8);
    }

    f32x4 o[2][4];
#pragma unroll
    for (int i = 0; i < 2; ++i)
#pragma unroll
        for (int t = 0; t < 4; ++t) o[i][t] = (f32x4){0.f, 0.f, 0.f, 0.f};
    float lsum[2][4] = {{0.f,0.f,0.f,0.f},{0.f,0.f,0.f,0.f}};

    unsigned short* Pw = &ldsP[w][0];

    // LDS read offsets (halfs); swizzle matches gemm_qkv writer.
    int koff[4][2], voff[4][2];
#pragma unroll
    for (int t = 0; t < 4; ++t) {
        int pr = (t >> 1) * 32 + 2 * l15 + (t & 1);
        int sw = l15 & 7;
        koff[t][0] = pr * 64 + (((quad)     ^ sw) << 3);
        koff[t][1] = pr * 64 + (((4 + quad) ^ sw) << 3);
        int d = t * 16 + l15;
        int swv = (l15 >> 1) & 7;
        voff[t][0] = d * 64 + (((quad)     ^ swv) << 3);
        voff[t][1] = d * 64 + (((4 + quad) ^ swv) << 3);
    }

    // DMA: each of the 2 waves stages 4KB of K and 4KB of V per chunk
    const unsigned short* ksrc = KB + w * 2048 + lane * 8;
    const unsigned short* vsrc = VB + w * 2048 + lane * 8;
    unsigned short* kdst = &ldsK[0][w * 2048];
    unsigned short* vdst = &ldsV[0][w * 2048];

#define STAGE(buf, c) do { \
        _Pragma("unroll") \
        for (int i = 0; i < 4; ++i) { \
            gld_lds16(ksrc + (size_t)(c) * 4096 + i * 512, kdst + (buf) * 4096 + i * 512); \
            gld_lds16(vsrc + (size_t)(c) * 4096 + i * 512, vdst + (buf) * 4096 + i * 512); \
        } \
    } while (0)

    STAGE(0, 0);

    for (int c = 0; c < SQ / 64; ++c) {
        __syncthreads();                       // drains DMA for chunk c
        if (c < SQ / 64 - 1) STAGE((c + 1) & 1, c + 1);

        const unsigned short* Kl = &ldsK[c & 1][0];
        const unsigned short* Vl = &ldsV[c & 1][0];

        f32x4 s[2][4];
#pragma unroll
        for (int i = 0; i < 2; ++i)
#pragma unroll
            for (int t = 0; t < 4; ++t) s[i][t] = (f32x4){0.f, 0.f, 0.f, 0.f};

#pragma unroll
        for (int t = 0; t < 4; ++t) {
            bf16x8 k0 = load_bf16x8(Kl + koff[t][0]);
            bf16x8 k1 = load_bf16x8(Kl + koff[t][1]);
#pragma unroll
            for (int i = 0; i < 2; ++i) {
                s[i][t] = __builtin_amdgcn_mfma_f32_16x16x32_bf16(aq[i][0], k0, s[i][t], 0, 0, 0);
                s[i][t] = __builtin_amdgcn_mfma_f32_16x16x32_bf16(aq[i][1], k1, s[i][t], 0, 0, 0);
            }
        }

        // exp2 + packed P write (cols: sub*32 + 2*l15 + {0,1})
#pragma unroll
        for (int i = 0; i < 2; ++i)
#pragma unroll
            for (int sub = 0; sub < 2; ++sub)
#pragma unroll
                for (int r = 0; r < 4; ++r) {
                    float e0 = exp2f(s[i][2 * sub][r]);
                    float e1 = exp2f(s[i][2 * sub + 1][r]);
                    lsum[i][r] += e0 + e1;
                    *(unsigned*)(Pw + (i * 16 + quad * 4 + r) * 72 + sub * 32 + l15 * 2)
                        = pack_bf16(e0, e1);
                }

        bf16x8 pf[2][2];
#pragma unroll
        for (int i = 0; i < 2; ++i) {
            pf[i][0] = load_bf16x8(Pw + (i * 16 + l15) * 72 + quad * 8);
            pf[i][1] = load_bf16x8(Pw + (i * 16 + l15) * 72 + 32 + quad * 8);
        }

#pragma unroll
        for (int t = 0; t < 4; ++t) {
            bf16x8 v0 = load_bf16x8(Vl + voff[t][0]);
            bf16x8 v1 = load_bf16x8(Vl + voff[t][1]);
#pragma unroll
            for (int i = 0; i < 2; ++i) {
                o[i][t] = __builtin_amdgcn_mfma_f32_16x16x32_bf16(pf[i][0], v0, o[i][t], 0, 0, 0);
                o[i][t] = __builtin_amdgcn_mfma_f32_16x16x32_bf16(pf[i][1], v1, o[i][t], 0, 0, 0);
            }
        }
    }
#undef STAGE

    // epilogue: final l reduction; write O in FRAGMENT order for gemm_out
#pragma unroll
    for (int i = 0; i < 2; ++i)
#pragma unroll
        for (int r = 0; r < 4; ++r) {
            float l = lsum[i][r];
            l += __shfl_xor(l, 1);
            l += __shfl_xor(l, 2);
            l += __shfl_xor(l, 4);
            l += __shfl_xor(l, 8);
            float inv = 1.0f / l;
            int R   = b * SQ + q0 + i * 16 + quad * 4 + r;
            int mt  = R >> 4;
            int rin = quad * 4 + r;
#pragma unroll
            for (int t = 0; t < 4; ++t) {
                int ks    = h * 2 + (t >> 1);
                int quadp = ((t & 1) << 1) + (l15 >> 3);
                int j     = l15 & 7;
                Af[(size_t)(mt * KTILES + ks) * 512 + (size_t)((quadp << 4) + rin) * 8 + j]
                    = f2bf(o[i][t][r] * inv);
            }
        }
}

// ---------------- Output projection: 32x64 wave tiles, LDS-staged weights -----
__global__ __launch_bounds__(128) void gemm_out(const unsigned short* __restrict__ Af,
                                                const unsigned short* __restrict__ Ff,
                                                const float* __restrict__ bias,
                                                float* __restrict__ out) {
    __shared__ __align__(16) unsigned short ldsB[2][8192];   // 16KB x2

    int w    = threadIdx.x >> 6;
    int lane = threadIdx.x & 63;
    int l15  = lane & 15;
    int quad = lane >> 4;
    int m0 = blockIdx.y * 64 + w * 32;
    int nb = blockIdx.x;
    int mt0 = m0 >> 4;

    const unsigned short* Ap = Af + (size_t)mt0 * KTILES * 512 + lane * 8;
    const unsigned short* Bsrc = Ff + (size_t)nb * KTILES * 4 * 512 + (w * 8) * 512 + lane * 8;
    unsigned short* Bdst = &ldsB[0][(w * 8) * 512];

    f32x4 acc[2][4];
#pragma unroll
    for (int i = 0; i < 2; ++i)
#pragma unroll
        for (int t = 0; t < 4; ++t) acc[i][t] = (f32x4){0.f, 0.f, 0.f, 0.f};

#define BSTAGE(buf, c) do { \
        _Pragma("unroll") \
        for (int i = 0; i < 8; ++i) \
            gld_lds16(Bsrc + (size_t)(c) * 8192 + i * 512, Bdst + (buf) * 8192 + i * 512); \
    } while (0)

    BSTAGE(0, 0);

    for (int c = 0; c < 6; ++c) {
        __syncthreads();
        if (c < 5) BSTAGE((c + 1) & 1, c + 1);
        const unsigned short* Bl = &ldsB[c & 1][0];
#pragma unroll
        for (int k4 = 0; k4 < 4; ++k4) {
            bf16x8 a[2];
#pragma unroll
            for (int i = 0; i < 2; ++i)
                a[i] = load_bf16x8(Ap + ((size_t)i * KTILES + c * 4 + k4) * 512);
#pragma unroll
            for (int t = 0; t < 4; ++t) {
                bf16x8 bb = load_bf16x8(Bl + (k4 * 4 + t) * 512 + lane * 8);
#pragma unroll
                for (int i = 0; i < 2; ++i)
                    acc[i][t] = __builtin_amdgcn_mfma_f32_16x16x32_bf16(a[i], bb, acc[i][t], 0, 0, 0);
            }
        }
    }
#undef BSTAGE

#pragma unroll
    for (int t = 0; t < 4; ++t) {
        int col = nb * 64 + t * 16 + l15;
        float bv = bias[col];
#pragma unroll
        for (int i = 0; i < 2; ++i)
#pragma unroll
            for (int r = 0; r < 4; ++r) {
                int row = m0 + i * 16 + quad * 4 + r;
                out[(size_t)row * DM + col] = acc[i][t][r] + bv;
            }
    }
}

extern "C" void kernel_launch(void* const* d_in, const int* in_sizes, int n_in,
                              void* d_out, int out_size, void* d_ws, size_t ws_size,
                              hipStream_t stream) {
    const float* query = (const float*)d_in[0];
    const float* key   = (const float*)d_in[1];
    const float* value = (const float*)d_in[2];
    const float* Wq = (const float*)d_in[3];  const float* bq = (const float*)d_in[4];
    const float* Wk = (const float*)d_in[5];  const float* bk = (const float*)d_in[6];
    const float* Wv = (const float*)d_in[7];  const float* bv = (const float*)d_in[8];
    const float* Wo = (const float*)d_in[9];  const float* bo = (const float*)d_in[10];

    const size_t NX = (size_t)ROWS * DM;        // 3,145,728
    const size_t NW = (size_t)DM * DM;          // 589,824
    unsigned short* Xq  = (unsigned short*)d_ws;   // frag(query); reused as frag(attn-out)
    unsigned short* Xk  = Xq  + NX;
    unsigned short* Xv  = Xk  + NX;
    unsigned short* Qb  = Xv  + NX;                // [B,H,S,DK]
    unsigned short* Kb  = Qb  + NX;                // blocked+swizzled
    unsigned short* Vt  = Kb  + NX;                // blocked+swizzled
    unsigned short* Wtq = Vt  + NX;
    unsigned short* Wtk = Wtq + NW;
    unsigned short* Wtv = Wtk + NW;
    unsigned short* Wto = Wtv + NW;

    cvt_frag3<<<dim3((unsigned)(NX / 8 / 256), 1, 3), 256, 0, stream>>>(
        query, key, value, Xq, Xk, Xv);

    wt_frag4<<<dim3((unsigned)(NW / 8 / 256), 1, 4), 256, 0, stream>>>(
        Wq, Wk, Wv, Wo, Wtq, Wtk, Wtv, Wto);

    gemm_qkv<<<dim3(DM / 64, ROWS / 128, 3), 128, 0, stream>>>(
        Xq, Xk, Xv, Wtq, Wtk, Wtv, bq, bk, bv, Qb, Kb, Vt);

    flash_attn<<<dim3(SQ / 64, HEADS, BATCH), 128, 0, stream>>>(Qb, Kb, Vt, Xq);

    gemm_out<<<dim3(DM / 64, ROWS / 64), 128, 0, stream>>>(Xq, Wto, bo, (float*)d_out);
}

// Round 7
// 208.262 us; speedup vs baseline: 1.1209x; 1.1209x over previous
//
#include <hip/hip_runtime.h>
#include <hip/hip_bf16.h>

// Problem constants
#define DM     768
#define HEADS  12
#define DK     64
#define SQ     2048
#define BATCH  2
#define ROWS   4096   // BATCH * SQ
#define KTILES 24     // DM / 32

typedef __attribute__((ext_vector_type(4))) float f32x4;
typedef __bf16 bf16x8 __attribute__((ext_vector_type(8)));
typedef unsigned short u16x8 __attribute__((ext_vector_type(8)));

#define QSCALE 0.180336880f   // (1/sqrt(64)) * log2(e): scores feed exp2f

static __device__ __forceinline__ unsigned short f2bf(float f) {
    union { float f; unsigned u; } v; v.f = f;
    unsigned u = v.u;
    unsigned lsb = (u >> 16) & 1u;
    u += 0x7fffu + lsb;              // round-to-nearest-even
    return (unsigned short)(u >> 16);
}

static __device__ __forceinline__ unsigned pack_bf16(float a, float b) {
    __hip_bfloat162 h = __float22bfloat162_rn(make_float2(a, b));  // v_cvt_pk_bf16_f32
    unsigned u;
    __builtin_memcpy(&u, &h, 4);
    return u;
}

static __device__ __forceinline__ bf16x8 load_bf16x8(const unsigned short* p) {
    u16x8 u = *(const u16x8*)p;      // 16B load
    return __builtin_bit_cast(bf16x8, u);
}

// Async global->LDS DMA: 64 lanes x 16B; LDS dest = uniform base + lane*16.
static __device__ __forceinline__ void gld_lds16(const unsigned short* g, unsigned short* l) {
    __builtin_amdgcn_global_load_lds((const __attribute__((address_space(1))) void*)g,
                                     (__attribute__((address_space(3))) void*)l,
                                     16, 0, 0);
}

// Explicit DMA drain. __syncthreads() alone does NOT guarantee each wave's
// global_load_lds has landed before the barrier: the compiler only emits the
// vmcnt wait where it sees an in-wave dependency, and a wave that stages data
// consumed ONLY by sibling waves may get its wait scheduled after the barrier
// (R6 failed with 4e-2 corruption from exactly this). Force the drain.
static __device__ __forceinline__ void drain_dma() {
    asm volatile("s_waitcnt vmcnt(0)" ::: "memory");
}

// ---------- fp32 -> bf16 convert into FRAGMENT-LINEAR order (3 tensors) -------
__global__ __launch_bounds__(256) void cvt_frag3(const float* __restrict__ X0,
                                                 const float* __restrict__ X1,
                                                 const float* __restrict__ X2,
                                                 unsigned short* __restrict__ A0,
                                                 unsigned short* __restrict__ A1,
                                                 unsigned short* __restrict__ A2) {
    int z = blockIdx.z;
    const float* X = z == 0 ? X0 : z == 1 ? X1 : X2;
    unsigned short* A = z == 0 ? A0 : z == 1 ? A1 : A2;
    int p = blockIdx.x * 256 + threadIdx.x;
    int lane = p & 63;
    int g = p >> 6;
    int ks = g % KTILES;
    int mt = g / KTILES;
    int row = mt * 16 + (lane & 15);
    int k   = ks * 32 + (lane >> 4) * 8;
    const float* src = X + (size_t)row * DM + k;
    float4 v0 = *(const float4*)src;
    float4 v1 = *(const float4*)(src + 4);
    u16x8 o;
    o[0]=f2bf(v0.x); o[1]=f2bf(v0.y); o[2]=f2bf(v0.z); o[3]=f2bf(v0.w);
    o[4]=f2bf(v1.x); o[5]=f2bf(v1.y); o[6]=f2bf(v1.z); o[7]=f2bf(v1.w);
    *(u16x8*)(A + (size_t)p * 8) = o;
}

// ---------- weight transpose+convert into FRAGMENT-LINEAR order (4 weights) ---
__global__ __launch_bounds__(256) void wt_frag4(const float* __restrict__ W0,
                                                const float* __restrict__ W1,
                                                const float* __restrict__ W2,
                                                const float* __restrict__ W3,
                                                unsigned short* __restrict__ F0,
                                                unsigned short* __restrict__ F1,
                                                unsigned short* __restrict__ F2,
                                                unsigned short* __restrict__ F3) {
    int z = blockIdx.z;
    const float* W = z == 0 ? W0 : z == 1 ? W1 : z == 2 ? W2 : W3;
    unsigned short* F = z == 0 ? F0 : z == 1 ? F1 : z == 2 ? F2 : F3;
    int p = blockIdx.x * 256 + threadIdx.x;
    int lane = p & 63;
    int t = (p >> 6) & 3;
    int g = p >> 8;
    int ks = g % KTILES;
    int nb = g / KTILES;
    int n = nb * 64 + t * 16 + (lane & 15);
    int k = ks * 32 + (lane >> 4) * 8;
    u16x8 o;
#pragma unroll
    for (int j = 0; j < 8; ++j) o[j] = f2bf(W[(size_t)(k + j) * DM + n]);
    *(u16x8*)(F + (size_t)p * 8) = o;
}

// ---------------- QKV GEMM (fused): 4 waves x (32 rows x 64 cols) -------------
// Block = 256 thr = 128 rows x 64 cols. Weight frags for 4 k-steps (16KB)
// DMA'd to LDS double-buffered (staging split across 4 waves); A direct from
// global (frag-linear, coalesced).
__global__ __launch_bounds__(256) void gemm_qkv(const unsigned short* __restrict__ A0,
                                                const unsigned short* __restrict__ A1,
                                                const unsigned short* __restrict__ A2,
                                                const unsigned short* __restrict__ F0,
                                                const unsigned short* __restrict__ F1,
                                                const unsigned short* __restrict__ F2,
                                                const float* __restrict__ b0,
                                                const float* __restrict__ b1,
                                                const float* __restrict__ b2,
                                                unsigned short* __restrict__ Qo,
                                                unsigned short* __restrict__ Ko,
                                                unsigned short* __restrict__ Vo) {
    __shared__ __align__(16) unsigned short ldsB[2][8192];   // 16KB x2

    int z = blockIdx.z;
    const unsigned short* A = z == 0 ? A0 : z == 1 ? A1 : A2;
    const unsigned short* F = z == 0 ? F0 : z == 1 ? F1 : F2;
    const float* bias        = z == 0 ? b0 : z == 1 ? b1 : b2;

    int w    = threadIdx.x >> 6;
    int lane = threadIdx.x & 63;
    int l15  = lane & 15;
    int quad = lane >> 4;
    int m0 = blockIdx.y * 128 + w * 32;
    int nb = blockIdx.x;
    int mt0 = m0 >> 4;

    const unsigned short* Ap = A + (size_t)mt0 * KTILES * 512 + lane * 8;
    const unsigned short* Bsrc = F + (size_t)nb * KTILES * 4 * 512 + w * 2048 + lane * 8;
    unsigned short* Bdst = &ldsB[0][w * 2048];

    f32x4 acc[2][4];
#pragma unroll
    for (int i = 0; i < 2; ++i)
#pragma unroll
        for (int t = 0; t < 4; ++t) acc[i][t] = (f32x4){0.f, 0.f, 0.f, 0.f};

#define BSTAGE(buf, c) do { \
        _Pragma("unroll") \
        for (int j = 0; j < 4; ++j) \
            gld_lds16(Bsrc + (size_t)(c) * 8192 + j * 512, Bdst + (buf) * 8192 + j * 512); \
    } while (0)

    BSTAGE(0, 0);

    for (int c = 0; c < 6; ++c) {
        drain_dma();          // publish this wave's BSTAGE(c) before the barrier
        __syncthreads();
        if (c < 5) BSTAGE((c + 1) & 1, c + 1);
        const unsigned short* Bl = &ldsB[c & 1][0];
#pragma unroll
        for (int k4 = 0; k4 < 4; ++k4) {
            bf16x8 a[2];
#pragma unroll
            for (int i = 0; i < 2; ++i)
                a[i] = load_bf16x8(Ap + ((size_t)i * KTILES + c * 4 + k4) * 512);
#pragma unroll
            for (int t = 0; t < 4; ++t) {
                bf16x8 bb = load_bf16x8(Bl + (k4 * 4 + t) * 512 + lane * 8);
#pragma unroll
                for (int i = 0; i < 2; ++i)
                    acc[i][t] = __builtin_amdgcn_mfma_f32_16x16x32_bf16(a[i], bb, acc[i][t], 0, 0, 0);
            }
        }
    }
#undef BSTAGE

    float scale = (z == 0) ? QSCALE : 1.0f;
#pragma unroll
    for (int t = 0; t < 4; ++t) {
        int col = nb * 64 + t * 16 + l15;
        float bv = bias[col];
        int h = col >> 6, d = col & (DK - 1);
#pragma unroll
        for (int i = 0; i < 2; ++i)
#pragma unroll
            for (int r = 0; r < 4; ++r) {
                int row = m0 + i * 16 + quad * 4 + r;
                float v = (acc[i][t][r] + bv) * scale;
                int bb = row >> 11, s = row & (SQ - 1);
                size_t bh = (size_t)(bb * HEADS + h);
                if (z == 0) {
                    Qo[(bh * SQ + s) * DK + d] = f2bf(v);
                } else if (z == 1) {
                    int sc = s & 63;
                    Ko[(bh * (SQ / 64) + (s >> 6)) * 4096 + sc * 64 +
                       (((d >> 3) ^ ((sc >> 1) & 7)) << 3) + (d & 7)] = f2bf(v);
                } else {
                    int sc = s & 63;
                    Vo[(bh * (SQ / 64) + (s >> 6)) * 4096 + d * 64 +
                       (((sc >> 3) ^ ((d >> 1) & 7)) << 3) + (sc & 7)] = f2bf(v);
                }
            }
    }
}

// ---------------- Flash attention v5b: chunk-parity wave pairs ----------------
// Block = 256 thr = 4 waves covering 64 q-rows. Wave (rg,par): q-rows
// rg*32..rg*32+32, key-chunks with c%2==par. ldsK/ldsV[par] hold the two
// in-flight chunks (both parities compute concurrently); 2 barriers per
// 128-key step; DMA split 4 ways; explicit vmcnt drain before the read
// barrier. Fixed-max exp2 softmax -> parity partials are additive; combined
// in-LDS at the end.
__global__ __launch_bounds__(256) void flash_attn(const unsigned short* __restrict__ Q,
                                                  const unsigned short* __restrict__ Kb,
                                                  const unsigned short* __restrict__ Vb,
                                                  unsigned short* __restrict__ Af) {
    __shared__ __align__(16) unsigned short ldsK[2][4096];    // 8KB per parity
    __shared__ __align__(16) unsigned short ldsV[2][4096];
    __shared__ __align__(16) unsigned short ldsP[4][32 * 72]; // per-wave P

    int w    = threadIdx.x >> 6;
    int lane = threadIdx.x & 63;
    int l15  = lane & 15;
    int quad = lane >> 4;
    int rg   = w >> 1;        // row-group: q-rows rg*32..rg*32+31
    int par  = w & 1;         // chunk parity
    int b = blockIdx.z, h = blockIdx.y;
    int q0 = blockIdx.x * 64 + rg * 32;

    size_t bh = (size_t)(b * HEADS + h);
    const unsigned short* Qp = Q  + (bh * SQ + q0) * DK;
    const unsigned short* KB = Kb + bh * (SQ / 64) * 4096;
    const unsigned short* VB = Vb + bh * (SQ / 64) * 4096;

    bf16x8 aq[2][2];
#pragma unroll
    for (int i = 0; i < 2; ++i) {
        aq[i][0] = load_bf16x8(Qp + (i * 16 + l15) * DK + quad * 8);
        aq[i][1] = load_bf16x8(Qp + (i * 16 + l15) * DK + 32 + quad * 8);
    }

    f32x4 o[2][4];
#pragma unroll
    for (int i = 0; i < 2; ++i)
#pragma unroll
        for (int t = 0; t < 4; ++t) o[i][t] = (f32x4){0.f, 0.f, 0.f, 0.f};
    float lsum[2][4] = {{0.f,0.f,0.f,0.f},{0.f,0.f,0.f,0.f}};

    unsigned short* Pw = &ldsP[w][0];

    // LDS read offsets (halfs); swizzle matches gemm_qkv writer.
    int koff[4][2], voff[4][2];
#pragma unroll
    for (int t = 0; t < 4; ++t) {
        int pr = (t >> 1) * 32 + 2 * l15 + (t & 1);
        int sw = l15 & 7;
        koff[t][0] = pr * 64 + (((quad)     ^ sw) << 3);
        koff[t][1] = pr * 64 + (((4 + quad) ^ sw) << 3);
        int d = t * 16 + l15;
        int swv = (l15 >> 1) & 7;
        voff[t][0] = d * 64 + (((quad)     ^ swv) << 3);
        voff[t][1] = d * 64 + (((4 + quad) ^ swv) << 3);
    }

    // DMA: wave (rg,par) stages half rg of buffer par (4KB K + 4KB V per step).
    const unsigned short* ksrc = KB + rg * 2048 + lane * 8;
    const unsigned short* vsrc = VB + rg * 2048 + lane * 8;
    unsigned short* kdst = &ldsK[par][rg * 2048];
    unsigned short* vdst = &ldsV[par][rg * 2048];

#define STAGE(n) do { \
        _Pragma("unroll") \
        for (int j = 0; j < 4; ++j) { \
            gld_lds16(ksrc + (size_t)(n) * 4096 + j * 512, kdst + j * 512); \
            gld_lds16(vsrc + (size_t)(n) * 4096 + j * 512, vdst + j * 512); \
        } \
    } while (0)

    STAGE(par);   // chunks 0 (buf0) and 1 (buf1)

    const unsigned short* Kl = &ldsK[par][0];
    const unsigned short* Vl = &ldsV[par][0];

    for (int s = 0; s < 16; ++s) {
        drain_dma();                     // publish own DMA before the barrier
        __syncthreads();                 // staged data visible to both rg waves

        f32x4 sc[2][4];
#pragma unroll
        for (int i = 0; i < 2; ++i)
#pragma unroll
            for (int t = 0; t < 4; ++t) sc[i][t] = (f32x4){0.f, 0.f, 0.f, 0.f};

#pragma unroll
        for (int t = 0; t < 4; ++t) {
            bf16x8 k0 = load_bf16x8(Kl + koff[t][0]);
            bf16x8 k1 = load_bf16x8(Kl + koff[t][1]);
#pragma unroll
            for (int i = 0; i < 2; ++i) {
                sc[i][t] = __builtin_amdgcn_mfma_f32_16x16x32_bf16(aq[i][0], k0, sc[i][t], 0, 0, 0);
                sc[i][t] = __builtin_amdgcn_mfma_f32_16x16x32_bf16(aq[i][1], k1, sc[i][t], 0, 0, 0);
            }
        }

        // exp2 + packed P write (cols: sub*32 + 2*l15 + {0,1})
#pragma unroll
        for (int i = 0; i < 2; ++i)
#pragma unroll
            for (int sub = 0; sub < 2; ++sub)
#pragma unroll
                for (int r = 0; r < 4; ++r) {
                    float e0 = exp2f(sc[i][2 * sub][r]);
                    float e1 = exp2f(sc[i][2 * sub + 1][r]);
                    lsum[i][r] += e0 + e1;
                    *(unsigned*)(Pw + (i * 16 + quad * 4 + r) * 72 + sub * 32 + l15 * 2)
                        = pack_bf16(e0, e1);
                }

        bf16x8 pf[2][2];
#pragma unroll
        for (int i = 0; i < 2; ++i) {
            pf[i][0] = load_bf16x8(Pw + (i * 16 + l15) * 72 + quad * 8);
            pf[i][1] = load_bf16x8(Pw + (i * 16 + l15) * 72 + 32 + quad * 8);
        }

#pragma unroll
        for (int t = 0; t < 4; ++t) {
            bf16x8 v0 = load_bf16x8(Vl + voff[t][0]);
            bf16x8 v1 = load_bf16x8(Vl + voff[t][1]);
#pragma unroll
            for (int i = 0; i < 2; ++i) {
                o[i][t] = __builtin_amdgcn_mfma_f32_16x16x32_bf16(pf[i][0], v0, o[i][t], 0, 0, 0);
                o[i][t] = __builtin_amdgcn_mfma_f32_16x16x32_bf16(pf[i][1], v1, o[i][t], 0, 0, 0);
            }
        }

        __syncthreads();                 // all reads of both buffers done
        if (s < 15) STAGE(2 * s + 2 + par);
    }
#undef STAGE

    // -------- parity combine (unnormalized partials are additive) --------
    float* fO = (float*)&ldsK[0][0];     // 32 rows x 64 cols fp32 per rg (16KB)
    float* fL = (float*)&ldsV[0][0];     // 32 rows x 16 lanes fp32 per rg
    if (par == 1) {
#pragma unroll
        for (int i = 0; i < 2; ++i)
#pragma unroll
            for (int r = 0; r < 4; ++r) {
                int rowin = i * 16 + quad * 4 + r;
#pragma unroll
                for (int t = 0; t < 4; ++t)
                    fO[rg * 2048 + rowin * 64 + t * 16 + l15] = o[i][t][r];
                fL[rg * 512 + rowin * 16 + l15] = lsum[i][r];
            }
    }
    __syncthreads();
    if (par == 0) {
#pragma unroll
        for (int i = 0; i < 2; ++i)
#pragma unroll
            for (int r = 0; r < 4; ++r) {
                int rowin = i * 16 + quad * 4 + r;
                float l = lsum[i][r] + fL[rg * 512 + rowin * 16 + l15];
                l += __shfl_xor(l, 1);
                l += __shfl_xor(l, 2);
                l += __shfl_xor(l, 4);
                l += __shfl_xor(l, 8);
                float inv = 1.0f / l;
                int R  = b * SQ + q0 + rowin;
                int mt = R >> 4;
#pragma unroll
                for (int t = 0; t < 4; ++t) {
                    float val = o[i][t][r] + fO[rg * 2048 + rowin * 64 + t * 16 + l15];
                    int ks    = h * 2 + (t >> 1);
                    int quadp = ((t & 1) << 1) + (l15 >> 3);
                    int j     = l15 & 7;
                    Af[(size_t)(mt * KTILES + ks) * 512 +
                       (size_t)((quadp << 4) + (rowin & 15)) * 8 + j] = f2bf(val * inv);
                }
            }
    }
}

// ---------------- Output projection: 4 waves x (16 rows x 64 cols) ------------
__global__ __launch_bounds__(256) void gemm_out(const unsigned short* __restrict__ Af,
                                                const unsigned short* __restrict__ Ff,
                                                const float* __restrict__ bias,
                                                float* __restrict__ out) {
    __shared__ __align__(16) unsigned short ldsB[2][8192];   // 16KB x2

    int w    = threadIdx.x >> 6;
    int lane = threadIdx.x & 63;
    int l15  = lane & 15;
    int quad = lane >> 4;
    int m0 = blockIdx.y * 64 + w * 16;
    int nb = blockIdx.x;
    int mt = m0 >> 4;

    const unsigned short* Ap = Af + (size_t)mt * KTILES * 512 + lane * 8;
    const unsigned short* Bsrc = Ff + (size_t)nb * KTILES * 4 * 512 + w * 2048 + lane * 8;
    unsigned short* Bdst = &ldsB[0][w * 2048];

    f32x4 acc[4];
#pragma unroll
    for (int t = 0; t < 4; ++t) acc[t] = (f32x4){0.f, 0.f, 0.f, 0.f};

#define BSTAGE(buf, c) do { \
        _Pragma("unroll") \
        for (int j = 0; j < 4; ++j) \
            gld_lds16(Bsrc + (size_t)(c) * 8192 + j * 512, Bdst + (buf) * 8192 + j * 512); \
    } while (0)

    BSTAGE(0, 0);

    for (int c = 0; c < 6; ++c) {
        drain_dma();          // publish this wave's BSTAGE(c) before the barrier
        __syncthreads();
        if (c < 5) BSTAGE((c + 1) & 1, c + 1);
        const unsigned short* Bl = &ldsB[c & 1][0];
#pragma unroll
        for (int k4 = 0; k4 < 4; ++k4) {
            bf16x8 a = load_bf16x8(Ap + (size_t)(c * 4 + k4) * 512);
#pragma unroll
            for (int t = 0; t < 4; ++t) {
                bf16x8 bb = load_bf16x8(Bl + (k4 * 4 + t) * 512 + lane * 8);
                acc[t] = __builtin_amdgcn_mfma_f32_16x16x32_bf16(a, bb, acc[t], 0, 0, 0);
            }
        }
    }
#undef BSTAGE

#pragma unroll
    for (int t = 0; t < 4; ++t) {
        int col = nb * 64 + t * 16 + l15;
        float bv = bias[col];
#pragma unroll
        for (int r = 0; r < 4; ++r) {
            int row = m0 + quad * 4 + r;
            out[(size_t)row * DM + col] = acc[t][r] + bv;
        }
    }
}

extern "C" void kernel_launch(void* const* d_in, const int* in_sizes, int n_in,
                              void* d_out, int out_size, void* d_ws, size_t ws_size,
                              hipStream_t stream) {
    const float* query = (const float*)d_in[0];
    const float* key   = (const float*)d_in[1];
    const float* value = (const float*)d_in[2];
    const float* Wq = (const float*)d_in[3];  const float* bq = (const float*)d_in[4];
    const float* Wk = (const float*)d_in[5];  const float* bk = (const float*)d_in[6];
    const float* Wv = (const float*)d_in[7];  const float* bv = (const float*)d_in[8];
    const float* Wo = (const float*)d_in[9];  const float* bo = (const float*)d_in[10];

    const size_t NX = (size_t)ROWS * DM;        // 3,145,728
    const size_t NW = (size_t)DM * DM;          // 589,824
    unsigned short* Xq  = (unsigned short*)d_ws;   // frag(query); reused as frag(attn-out)
    unsigned short* Xk  = Xq  + NX;
    unsigned short* Xv  = Xk  + NX;
    unsigned short* Qb  = Xv  + NX;                // [B,H,S,DK]
    unsigned short* Kb  = Qb  + NX;                // blocked+swizzled
    unsigned short* Vt  = Kb  + NX;                // blocked+swizzled
    unsigned short* Wtq = Vt  + NX;
    unsigned short* Wtk = Wtq + NW;
    unsigned short* Wtv = Wtk + NW;
    unsigned short* Wto = Wtv + NW;

    cvt_frag3<<<dim3((unsigned)(NX / 8 / 256), 1, 3), 256, 0, stream>>>(
        query, key, value, Xq, Xk, Xv);

    wt_frag4<<<dim3((unsigned)(NW / 8 / 256), 1, 4), 256, 0, stream>>>(
        Wq, Wk, Wv, Wo, Wtq, Wtk, Wtv, Wto);

    gemm_qkv<<<dim3(DM / 64, ROWS / 128, 3), 256, 0, stream>>>(
        Xq, Xk, Xv, Wtq, Wtk, Wtv, bq, bk, bv, Qb, Kb, Vt);

    flash_attn<<<dim3(SQ / 64, HEADS, BATCH), 256, 0, stream>>>(Qb, Kb, Vt, Xq);

    gemm_out<<<dim3(DM / 64, ROWS / 64), 256, 0, stream>>>(Xq, Wto, bo, (float*)d_out);
}